// Round 8
// baseline (219.615 us; speedup 1.0000x reference)
//
#include <hip/hip_runtime.h>
#include <math.h>

// Problem constants
#define B_  4
#define S_  2048
#define D_  1024
#define H_  16
#define DK_ 64

typedef __bf16 bf16x8 __attribute__((ext_vector_type(8)));
typedef float  f32x4  __attribute__((ext_vector_type(4)));

__device__ __forceinline__ unsigned short f2bf(float f) {
  unsigned int u = __builtin_bit_cast(unsigned int, f);
  u += 0x7fffu + ((u >> 16) & 1u);   // round to nearest even
  return (unsigned short)(u >> 16);
}

__device__ __forceinline__ unsigned short bfbits(float f) {
  __bf16 h = (__bf16)f;              // native cvt
  return __builtin_bit_cast(unsigned short, h);
}

__device__ __forceinline__ f32x4 mfma16(bf16x8 a, bf16x8 b, f32x4 c) {
  return __builtin_amdgcn_mfma_f32_16x16x32_bf16(a, b, c, 0, 0, 0);
}

__device__ __forceinline__ void gl_lds16(const unsigned short* g, unsigned short* l) {
  __builtin_amdgcn_global_load_lds(
      (const __attribute__((address_space(1))) void*)g,
      (__attribute__((address_space(3))) void*)l, 16, 0, 0);
}

#define MEMF  asm volatile("" ::: "memory")
#define BARR  do { MEMF; __builtin_amdgcn_s_barrier(); MEMF; } while (0)

// ---------------------------------------------------------------- casts
__global__ void SAA_cast_bf16(const float* __restrict__ src,
                              unsigned short* __restrict__ dst, int n4) {
  int i = blockIdx.x * blockDim.x + threadIdx.x;
  int stride = gridDim.x * blockDim.x;
  for (; i < n4; i += stride) {
    float4 v = reinterpret_cast<const float4*>(src)[i];
    ushort4 o;
    o.x = f2bf(v.x); o.y = f2bf(v.y); o.z = f2bf(v.z); o.w = f2bf(v.w);
    reinterpret_cast<ushort4*>(dst)[i] = o;
  }
}

__global__ void SAA_cast4(const float* __restrict__ s0, const float* __restrict__ s1,
                          const float* __restrict__ s2, const float* __restrict__ s3,
                          unsigned short* __restrict__ d0, unsigned short* __restrict__ d1,
                          unsigned short* __restrict__ d2, unsigned short* __restrict__ d3,
                          int n4) {
  const float* src = (blockIdx.y == 0) ? s0 : (blockIdx.y == 1) ? s1
                   : (blockIdx.y == 2) ? s2 : s3;
  unsigned short* dst = (blockIdx.y == 0) ? d0 : (blockIdx.y == 1) ? d1
                      : (blockIdx.y == 2) ? d2 : d3;
  int i = blockIdx.x * blockDim.x + threadIdx.x;
  int stride = gridDim.x * blockDim.x;
  for (; i < n4; i += stride) {
    float4 v = reinterpret_cast<const float4*>(src)[i];
    ushort4 o;
    o.x = f2bf(v.x); o.y = f2bf(v.y); o.z = f2bf(v.z); o.w = f2bf(v.w);
    reinterpret_cast<ushort4*>(dst)[i] = o;
  }
}

// ---------------------------------------------------------------- fused QKV GEMM
// 8-phase 256x256 template (T3+T4+T5): BM=BN=256, BK=64, 512 threads (8 waves,
// 2m x 4n), 4 phases per K-tile with raw s_barrier + COUNTED vmcnt (loads stay
// in flight across barriers; never drained to 0 in steady state).
// N=3072 fused (mat = n-tile>>2 selects Wq/Wk/Wv). XOR-chunk-swizzled LDS.
// K rows pre-scaled by 0.125*log2(e)*rw[s] (scores leave QK^T in exp2-domain).
// Staging schedule (tile T, slot T&1):  B(T+1) at ph0/ph1 (2 loads each),
// A(T+2) at ph3 (4 loads). Boundary wait vmcnt(4) (A(T+2) stays in flight).
// A-slot reuse guarded by lgkmcnt(0) at ph2-end (A(T) reads fully drained
// before ph3 issues A(T+2) into the same slot).
__global__ __launch_bounds__(512, 2)
void SAA_gemm_qkv(const unsigned short* __restrict__ Xb,
                  const unsigned short* __restrict__ Wqb,
                  const unsigned short* __restrict__ Wkb,
                  const unsigned short* __restrict__ Wvb,
                  const float* __restrict__ bq,
                  const float* __restrict__ bk,
                  const float* __restrict__ bv,
                  const float* __restrict__ rw,
                  unsigned short* __restrict__ Qo,
                  unsigned short* __restrict__ Ko,
                  unsigned short* __restrict__ Vto)
{
  const int K = D_;
  __shared__ __attribute__((aligned(16))) unsigned short sA[2][256 * 64];  // 2x32KB
  __shared__ __attribute__((aligned(16))) unsigned short sB[2][256 * 64];  // 2x32KB

  const int t = threadIdx.x;
  const int w = t >> 6, l = t & 63;
  const int wr = w >> 2, wc = w & 3;          // 2 x 4 wave grid
  const int lr = l & 15, lg = l >> 4;
  const int r7 = lr & 7;

  const int nt = blockIdx.x;                  // 0..11
  const int mt = blockIdx.y;                  // 0..31
  const int mat = nt >> 2;
  const unsigned short* gW = (mat == 0) ? Wqb : ((mat == 1) ? Wkb : Wvb);
  const unsigned short* gA = Xb + (size_t)(mt * 256) * K;
  const unsigned short* gB = gW + (size_t)((nt & 3) * 256) * K;

  const int sr = t >> 3;                      // staging row within 64-row chunk
  const int soff = ((t & 7) ^ (sr & 7)) * 8;  // pre-swizzled source chunk

  // stage rows [rb, rb+64) of K-offset k0 into dst (one 8KB gl_lds sweep)
#define STG(dst, g, k0, rb) \
  gl_lds16((g) + (size_t)((rb) + sr) * K + (k0) + soff, (dst) + (rb) * 64 + t * 8)

  // prologue: A(0), B(0), A(1), B(1)  (16 loads)
  STG(sA[0], gA, 0, 0);  STG(sA[0], gA, 0, 64);  STG(sA[0], gA, 0, 128);  STG(sA[0], gA, 0, 192);
  STG(sB[0], gB, 0, 0);  STG(sB[0], gB, 0, 64);  STG(sB[0], gB, 0, 128);  STG(sB[0], gB, 0, 192);
  STG(sA[1], gA, 64, 0); STG(sA[1], gA, 64, 64); STG(sA[1], gA, 64, 128); STG(sA[1], gA, 64, 192);
  STG(sB[1], gB, 64, 0); STG(sB[1], gB, 64, 64); STG(sB[1], gB, 64, 128); STG(sB[1], gB, 64, 192);
  asm volatile("s_waitcnt vmcnt(8)" ::: "memory");   // A(0),B(0) landed; A(1),B(1) in flight
  BARR;

  f32x4 acc[8][4] = {};

#define LDB(n, ks) *reinterpret_cast<const bf16x8*>( \
    &Bt[(wc * 64 + (n) * 16 + lr) * 64 + ((((ks) * 4 + lg) ^ r7) << 3)])
#define LDA(m, ks) *reinterpret_cast<const bf16x8*>( \
    &At[(wr * 128 + (m) * 16 + lr) * 64 + ((((ks) * 4 + lg) ^ r7) << 3)])
#define MFMA_PAIR(m0) \
  do { _Pragma("unroll") for (int mm = (m0); mm < (m0) + 2; ++mm) \
       _Pragma("unroll") for (int n = 0; n < 4; ++n) { \
         acc[mm][n] = mfma16(afr[mm][0], bfr[n][0], acc[mm][n]); \
         acc[mm][n] = mfma16(afr[mm][1], bfr[n][1], acc[mm][n]); } } while (0)

#pragma unroll 2
  for (int T = 0; T < 16; ++T) {
    const unsigned short* At = sA[T & 1];
    const unsigned short* Bt = sB[T & 1];
    const int kn1 = (T + 1) * 64, kn2 = (T + 2) * 64;
    unsigned short* nB = sB[(T + 1) & 1];
    unsigned short* nA = sA[T & 1];           // slot (T+2)&1 == T&1
    const bool stB = (T >= 1) && (T + 1 < 16);
    const bool stA = (T + 2 < 16);
    bf16x8 bfr[4][2], afr[8][2];

    // ---- phase 0: read B(all) + A m0,m1; stage B(T+1) rows 0-127
#pragma unroll
    for (int n = 0; n < 4; ++n) { bfr[n][0] = LDB(n, 0); bfr[n][1] = LDB(n, 1); }
#pragma unroll
    for (int m = 0; m < 2; ++m) { afr[m][0] = LDA(m, 0); afr[m][1] = LDA(m, 1); }
    if (stB) { STG(nB, gB, kn1, 0); STG(nB, gB, kn1, 64); }
    BARR;
    __builtin_amdgcn_s_setprio(1); MFMA_PAIR(0); __builtin_amdgcn_s_setprio(0);
    BARR;

    // ---- phase 1: read A m2,m3; stage B(T+1) rows 128-255
#pragma unroll
    for (int m = 2; m < 4; ++m) { afr[m][0] = LDA(m, 0); afr[m][1] = LDA(m, 1); }
    if (stB) { STG(nB, gB, kn1, 128); STG(nB, gB, kn1, 192); }
    BARR;
    __builtin_amdgcn_s_setprio(1); MFMA_PAIR(2); __builtin_amdgcn_s_setprio(0);
    BARR;

    // ---- phase 2: read A m4..m7
#pragma unroll
    for (int m = 4; m < 8; ++m) { afr[m][0] = LDA(m, 0); afr[m][1] = LDA(m, 1); }
    BARR;
    __builtin_amdgcn_s_setprio(1); MFMA_PAIR(4); __builtin_amdgcn_s_setprio(0);
    asm volatile("s_waitcnt lgkmcnt(0)" ::: "memory");   // drain A(T) reads before restage
    BARR;

    // ---- phase 3: stage A(T+2) (slot T&1, now free)
    if (stA) { STG(nA, gA, kn2, 0); STG(nA, gA, kn2, 64);
               STG(nA, gA, kn2, 128); STG(nA, gA, kn2, 192); }
    BARR;
    __builtin_amdgcn_s_setprio(1); MFMA_PAIR(6); __builtin_amdgcn_s_setprio(0);
    if (T < 14)       asm volatile("s_waitcnt vmcnt(4)" ::: "memory");  // A(T+2) stays in flight
    else if (T == 14) asm volatile("s_waitcnt vmcnt(0)" ::: "memory");  // epilogue drain
    BARR;
  }
#undef STG
#undef LDA
#undef LDB

  // epilogue: bias add, (K: reweight), cast, scatter into attention layouts
  const float* bias = (mat == 0) ? bq : ((mat == 1) ? bk : bv);
  const int colbase = (nt & 3) * 256 + wc * 64;
  const int rowbase = mt * 256 + wr * 128;
#pragma unroll
  for (int n = 0; n < 4; ++n) {
    const int c = colbase + n * 16 + lr;      // within-mat feature 0..1023
    const int h = c >> 6, dk = c & 63;
    const float bs = bias[c];
#pragma unroll
    for (int m = 0; m < 8; ++m) {
#pragma unroll
      for (int r = 0; r < 4; ++r) {
        const int row = rowbase + m * 16 + lg * 4 + r;    // token 0..8191
        const int b = row >> 11, s = row & 2047;
        float v = acc[m][n][r] + bs;
        if (mat == 1) v *= 0.18033688011112042f * rw[row];   // 0.125*log2(e)*rw
        const unsigned short val = bfbits(v);
        if (mat == 2)
          Vto[(((size_t)b * H_ + h) * DK_ + dk) * S_ + s] = val;   // [B,H,DK,S]
        else if (mat == 0)
          Qo[(((size_t)b * H_ + h) * S_ + s) * DK_ + dk] = val;    // [B,H,S,DK]
        else
          Ko[(((size_t)b * H_ + h) * S_ + s) * DK_ + dk] = val;
      }
    }
  }
}

// ---------------------------------------------------------------- flash attention
// (unchanged from round 7: 8 waves x 16 q-rows, paired q-blocks, KV=64 dbuf,
// exp2-domain scores, no running max, XOR-swizzled LDS)
__global__ __launch_bounds__(512)
void SAA_attn(const unsigned short* __restrict__ Q,
              const unsigned short* __restrict__ Kb,
              const unsigned short* __restrict__ Vt,
              const int* __restrict__ maskp,
              unsigned short* __restrict__ Cb)
{
  const int pairid = blockIdx.x;                 // 0..7
  const int h = blockIdx.y, b = blockIdx.z;
  const int t = threadIdx.x, w = t >> 6, l = t & 63;
  const int lr = l & 15, lg = l >> 4;
  const int mask = maskp[0];

  __shared__ __attribute__((aligned(16))) unsigned short Kt[2][64 * 64];
  __shared__ __attribute__((aligned(16))) unsigned short Vl[2][64 * 64];
  __shared__ __attribute__((aligned(16))) unsigned short Pl[8][16 * 64];

  const size_t bh = (size_t)b * H_ + h;
  const unsigned short* Qbh = Q + bh * S_ * DK_;
  const unsigned short* Kbh = Kb + bh * S_ * DK_;
  const unsigned short* Vbh = Vt + bh * DK_ * S_;
  unsigned short* Pw = &Pl[w][0];

  const int r0 = t >> 3, cc0 = t & 7;
  const int sw0 = (cc0 ^ (r0 & 7)) * 8;

  for (int half = 0; half < 2; ++half) {
    const int qb = half ? (15 - pairid) : pairid;
    const int q0 = qb * 128;
    const int wq = q0 + w * 16;

    bf16x8 qf[2];
#pragma unroll
    for (int ks = 0; ks < 2; ks++)
      qf[ks] = *reinterpret_cast<const bf16x8*>(
          &Qbh[(size_t)(wq + lr) * DK_ + ks * 32 + lg * 8]);

    f32x4 acc[4] = {};
    float lrun[4] = {0.f, 0.f, 0.f, 0.f};

    const int nkt = mask ? (qb * 2 + 2) : (S_ / 64);
    const int wqmax = wq + 15;

    __syncthreads();

    gl_lds16(Kbh + (size_t)r0 * DK_ + sw0, &Kt[0][t * 8]);
    gl_lds16(Vbh + (size_t)r0 * S_ + sw0,  &Vl[0][t * 8]);
    int cur = 0;

    for (int kt = 0; kt < nkt; ++kt) {
      __syncthreads();
      if (kt + 1 < nkt) {
        const int kn = (kt + 1) * 64;
        const int nb = cur ^ 1;
        gl_lds16(Kbh + (size_t)(kn + r0) * DK_ + sw0, &Kt[nb][t * 8]);
        gl_lds16(Vbh + (size_t)r0 * S_ + kn + sw0,    &Vl[nb][t * 8]);
      }

      const int k0 = kt * 64;
      const bool active = (!mask) || (k0 <= wqmax);
      if (active) {
        const unsigned short* Kc = &Kt[cur][0];
        const unsigned short* Vc = &Vl[cur][0];

        f32x4 sc[4] = {};
#pragma unroll
        for (int ks = 0; ks < 2; ++ks) {
          const int swk = (((ks * 4 + lg) ^ (lr & 7)) << 3);
#pragma unroll
          for (int t2 = 0; t2 < 4; ++t2) {
            bf16x8 kf = *reinterpret_cast<const bf16x8*>(&Kc[(t2 * 16 + lr) * 64 + swk]);
            sc[t2] = mfma16(qf[ks], kf, sc[t2]);
          }
        }

        const bool needmask = mask && (k0 + 63 > wq);

#pragma unroll
        for (int r = 0; r < 4; r++) {
          const int row = wq + lg * 4 + r;
          float v0 = sc[0][r], v1 = sc[1][r];
          float v2 = sc[2][r], v3 = sc[3][r];
          if (needmask) {
            if (k0 + lr      > row) v0 = -1e30f;
            if (k0 + 16 + lr > row) v1 = -1e30f;
            if (k0 + 32 + lr > row) v2 = -1e30f;
            if (k0 + 48 + lr > row) v3 = -1e30f;
          }
          const float p0 = __builtin_amdgcn_exp2f(v0);
          const float p1 = __builtin_amdgcn_exp2f(v1);
          const float p2 = __builtin_amdgcn_exp2f(v2);
          const float p3 = __builtin_amdgcn_exp2f(v3);
          lrun[r] += (p0 + p1) + (p2 + p3);
          const int prow = lg * 4 + r;
          const int pr7 = prow & 7;
          const int pbase = prow * 64 + (lr & 7);
          const int hi = lr >> 3;
          Pw[pbase + (((0 + hi) ^ pr7) << 3)] = bfbits(p0);
          Pw[pbase + (((2 + hi) ^ pr7) << 3)] = bfbits(p1);
          Pw[pbase + (((4 + hi) ^ pr7) << 3)] = bfbits(p2);
          Pw[pbase + (((6 + hi) ^ pr7) << 3)] = bfbits(p3);
        }

#pragma unroll
        for (int ks = 0; ks < 2; ++ks) {
          const int swk = (((ks * 4 + lg) ^ (lr & 7)) << 3);
          bf16x8 pf = *reinterpret_cast<const bf16x8*>(&Pw[lr * 64 + swk]);
#pragma unroll
          for (int dt = 0; dt < 4; ++dt) {
            bf16x8 vf = *reinterpret_cast<const bf16x8*>(&Vc[(dt * 16 + lr) * 64 + swk]);
            acc[dt] = mfma16(pf, vf, acc[dt]);
          }
        }
      }
      cur ^= 1;
    }

#pragma unroll
    for (int r = 0; r < 4; r++) {
      float rs = lrun[r];
      rs += __shfl_xor(rs, 1);
      rs += __shfl_xor(rs, 2);
      rs += __shfl_xor(rs, 4);
      rs += __shfl_xor(rs, 8);
      lrun[r] = __builtin_amdgcn_rcpf(rs);
    }
#pragma unroll
    for (int dt = 0; dt < 4; dt++) {
#pragma unroll
      for (int r = 0; r < 4; r++) {
        const int row = wq + lg * 4 + r;
        const int col = h * DK_ + dt * 16 + lr;
        Cb[((size_t)b * S_ + row) * D_ + col] = bfbits(acc[dt][r] * lrun[r]);
      }
    }
  }
}

// ---------------------------------------------------------------- output GEMM
// (unchanged from round 7: 128x128, BK=64 XOR-swizzled)
__global__ __launch_bounds__(256)
void SAA_gemm_out(const unsigned short* __restrict__ Cb,
                  const unsigned short* __restrict__ Wob,
                  const float* __restrict__ bo,
                  float* __restrict__ Y)
{
  const int K = D_;
  __shared__ __attribute__((aligned(16))) unsigned short lA[128 * 64];
  __shared__ __attribute__((aligned(16))) unsigned short lB[128 * 64];

  const int t = threadIdx.x;
  const int w = t >> 6, l = t & 63;
  const int wr = w >> 1, wc = w & 1;
  const int lr = l & 15, lg = l >> 4;
  const int r7 = lr & 7;

  const int m0 = blockIdx.y * 128;
  const int n0 = blockIdx.x * 128;

  const unsigned short* gA = Cb + (size_t)m0 * K;
  const unsigned short* gB = Wob + (size_t)n0 * K;

  int srow[4], soff[4];
#pragma unroll
  for (int i = 0; i < 4; i++) {
    const int c = i * 256 + t;
    srow[i] = c >> 3;
    soff[i] = ((c & 7) ^ (srow[i] & 7)) * 8;
  }

  f32x4 acc[4][4] = {};

  for (int k0 = 0; k0 < K; k0 += 64) {
#pragma unroll
    for (int i = 0; i < 4; i++) {
      gl_lds16(gA + (size_t)srow[i] * K + k0 + soff[i], &lA[(i * 256 + t) * 8]);
      gl_lds16(gB + (size_t)srow[i] * K + k0 + soff[i], &lB[(i * 256 + t) * 8]);
    }
    __syncthreads();

#pragma unroll
    for (int ks = 0; ks < 2; ks++) {
      const int swk = ((ks * 4 + lg) ^ r7) * 8;
      bf16x8 af[4], bfr[4];
#pragma unroll
      for (int i = 0; i < 4; i++)
        af[i] = *reinterpret_cast<const bf16x8*>(&lA[(wr * 64 + i * 16 + lr) * 64 + swk]);
#pragma unroll
      for (int j = 0; j < 4; j++)
        bfr[j] = *reinterpret_cast<const bf16x8*>(&lB[(wc * 64 + j * 16 + lr) * 64 + swk]);
#pragma unroll
      for (int i = 0; i < 4; i++)
#pragma unroll
        for (int j = 0; j < 4; j++)
          acc[i][j] = mfma16(af[i], bfr[j], acc[i][j]);
    }
    __syncthreads();
  }

#pragma unroll
  for (int j = 0; j < 4; j++) {
    const int col = n0 + wc * 64 + j * 16 + lr;
    const float bsv = bo[col];
#pragma unroll
    for (int i = 0; i < 4; i++) {
#pragma unroll
      for (int r = 0; r < 4; r++) {
        const int row = m0 + wr * 64 + i * 16 + lg * 4 + r;
        Y[(size_t)row * D_ + col] = acc[i][j][r] + bsv;
      }
    }
  }
}

// ---------------------------------------------------------------- launch
extern "C" void kernel_launch(void* const* d_in, const int* in_sizes, int n_in,
                              void* d_out, int out_size, void* d_ws, size_t ws_size,
                              hipStream_t stream) {
  const float* input = (const float*)d_in[0];
  const float* rw    = (const float*)d_in[1];
  const int*   maskp = (const int*)d_in[2];
  const float* Wq = (const float*)d_in[3];
  const float* bq = (const float*)d_in[4];
  const float* Wk = (const float*)d_in[5];
  const float* bk = (const float*)d_in[6];
  const float* Wv = (const float*)d_in[7];
  const float* bv = (const float*)d_in[8];
  const float* Wo = (const float*)d_in[9];
  const float* bo = (const float*)d_in[10];

  char* ws = (char*)d_ws;
  unsigned short* Xb  = (unsigned short*)(ws);                 // 16 MB (reused as Cb)
  unsigned short* Wqb = (unsigned short*)(ws + (16u << 20));   // 2 MB each
  unsigned short* Wkb = (unsigned short*)(ws + (18u << 20));
  unsigned short* Wvb = (unsigned short*)(ws + (20u << 20));
  unsigned short* Wob = (unsigned short*)(ws + (22u << 20));
  unsigned short* Qo  = (unsigned short*)(ws + (24u << 20));   // 16 MB
  unsigned short* Ko  = (unsigned short*)(ws + (40u << 20));   // 16 MB
  unsigned short* Vto = (unsigned short*)(ws + (56u << 20));   // 16 MB
  unsigned short* Cb  = Xb;   // Xb dead after QKV GEMM

  SAA_cast_bf16<<<2048, 256, 0, stream>>>(input, Xb, (B_ * S_ * D_) / 4);
  SAA_cast4<<<dim3(512, 4), 256, 0, stream>>>(Wq, Wk, Wv, Wo, Wqb, Wkb, Wvb, Wob,
                                              (D_ * D_) / 4);

  SAA_gemm_qkv<<<dim3(12, 32), 512, 0, stream>>>(Xb, Wqb, Wkb, Wvb, bq, bk, bv, rw,
                                                 Qo, Ko, Vto);
  SAA_attn<<<dim3(8, 16, 4), 512, 0, stream>>>(Qo, Ko, Vto, maskp, Cb);
  SAA_gemm_out<<<dim3(8, 64), 256, 0, stream>>>(Cb, Wob, bo, (float*)d_out);
}

// Round 9
// 182.382 us; speedup vs baseline: 1.2042x; 1.2042x over previous
//
#include <hip/hip_runtime.h>
#include <math.h>

// Problem constants
#define B_  4
#define S_  2048
#define D_  1024
#define H_  16
#define DK_ 64

typedef __bf16 bf16x8 __attribute__((ext_vector_type(8)));
typedef float  f32x4  __attribute__((ext_vector_type(4)));

__device__ __forceinline__ unsigned short f2bf(float f) {
  unsigned int u = __builtin_bit_cast(unsigned int, f);
  u += 0x7fffu + ((u >> 16) & 1u);   // round to nearest even
  return (unsigned short)(u >> 16);
}

__device__ __forceinline__ unsigned short bfbits(float f) {
  __bf16 h = (__bf16)f;              // native cvt
  return __builtin_bit_cast(unsigned short, h);
}

__device__ __forceinline__ f32x4 mfma16(bf16x8 a, bf16x8 b, f32x4 c) {
  return __builtin_amdgcn_mfma_f32_16x16x32_bf16(a, b, c, 0, 0, 0);
}

__device__ __forceinline__ void gl_lds16(const unsigned short* g, unsigned short* l) {
  __builtin_amdgcn_global_load_lds(
      (const __attribute__((address_space(1))) void*)g,
      (__attribute__((address_space(3))) void*)l, 16, 0, 0);
}

// ---------------------------------------------------------------- casts
__global__ void SAA_cast_bf16(const float* __restrict__ src,
                              unsigned short* __restrict__ dst, int n4) {
  int i = blockIdx.x * blockDim.x + threadIdx.x;
  int stride = gridDim.x * blockDim.x;
  for (; i < n4; i += stride) {
    float4 v = reinterpret_cast<const float4*>(src)[i];
    ushort4 o;
    o.x = f2bf(v.x); o.y = f2bf(v.y); o.z = f2bf(v.z); o.w = f2bf(v.w);
    reinterpret_cast<ushort4*>(dst)[i] = o;
  }
}

__global__ void SAA_cast4(const float* __restrict__ s0, const float* __restrict__ s1,
                          const float* __restrict__ s2, const float* __restrict__ s3,
                          unsigned short* __restrict__ d0, unsigned short* __restrict__ d1,
                          unsigned short* __restrict__ d2, unsigned short* __restrict__ d3,
                          int n4) {
  const float* src = (blockIdx.y == 0) ? s0 : (blockIdx.y == 1) ? s1
                   : (blockIdx.y == 2) ? s2 : s3;
  unsigned short* dst = (blockIdx.y == 0) ? d0 : (blockIdx.y == 1) ? d1
                      : (blockIdx.y == 2) ? d2 : d3;
  int i = blockIdx.x * blockDim.x + threadIdx.x;
  int stride = gridDim.x * blockDim.x;
  for (; i < n4; i += stride) {
    float4 v = reinterpret_cast<const float4*>(src)[i];
    ushort4 o;
    o.x = f2bf(v.x); o.y = f2bf(v.y); o.z = f2bf(v.z); o.w = f2bf(v.w);
    reinterpret_cast<ushort4*>(dst)[i] = o;
  }
}

// ---------------------------------------------------------------- fused QKV GEMM
// One block: 128x128 output tile for ALL THREE projections. 512 threads
// (8 waves, 4m x 2n; per wave 32x64 per mat). BK=64, chunk-XOR-swizzled LDS
// (0 conflicts, round-5/7 verified). PREFETCH double-buffer: stage(T+1) is
// issued right after the barrier and lands during compute(T) -- the vmcnt
// drain inside the next __syncthreads happens a full compute phase later
// (this is the overlap round 7 was missing).
// K rows pre-scaled by 0.125*log2(e)*rw[s] (scores leave QK^T in exp2-domain).
__global__ __launch_bounds__(512)
void SAA_gemm_qkv(const unsigned short* __restrict__ Xb,
                  const unsigned short* __restrict__ Wqb,
                  const unsigned short* __restrict__ Wkb,
                  const unsigned short* __restrict__ Wvb,
                  const float* __restrict__ bq,
                  const float* __restrict__ bk,
                  const float* __restrict__ bv,
                  const float* __restrict__ rw,
                  unsigned short* __restrict__ Qo,
                  unsigned short* __restrict__ Ko,
                  unsigned short* __restrict__ Vto)
{
  const int K = D_;
  __shared__ __attribute__((aligned(16))) unsigned short sA[2][128 * 64];      // 32 KB
  __shared__ __attribute__((aligned(16))) unsigned short sB[2][3][128 * 64];   // 96 KB

  const int t = threadIdx.x;
  const int w = t >> 6, l = t & 63;
  const int wm = w >> 1, wn = w & 1;          // 4m x 2n wave grid
  const int lr = l & 15, lg = l >> 4;
  const int r7 = lr & 7;

  const int m0 = blockIdx.y * 128;
  const int n0 = blockIdx.x * 128;

  const unsigned short* gA = Xb + (size_t)m0 * K;
  const unsigned short* gB0 = Wqb + (size_t)n0 * K;
  const unsigned short* gB1 = Wkb + (size_t)n0 * K;
  const unsigned short* gB2 = Wvb + (size_t)n0 * K;

  // staging: each 128x64 tile = 1024 16B-chunks; 512 threads -> 2 chunks each.
  // source pre-swizzled (chunk ^= row&7); gl_lds destination stays linear.
  int srow[2], soff[2];
#pragma unroll
  for (int i = 0; i < 2; i++) {
    const int c = i * 512 + t;
    srow[i] = c >> 3;
    soff[i] = ((c & 7) ^ (srow[i] & 7)) * 8;
  }

#define STAGE(s, k0)                                                          \
  do {                                                                        \
    _Pragma("unroll")                                                         \
    for (int i = 0; i < 2; i++) {                                             \
      const size_t go = (size_t)srow[i] * K + (k0) + soff[i];                 \
      const int dl = (i * 512 + t) * 8;                                       \
      gl_lds16(gA  + go, &sA[s][dl]);                                         \
      gl_lds16(gB0 + go, &sB[s][0][dl]);                                      \
      gl_lds16(gB1 + go, &sB[s][1][dl]);                                      \
      gl_lds16(gB2 + go, &sB[s][2][dl]);                                      \
    }                                                                         \
  } while (0)

  STAGE(0, 0);                                // prologue

  f32x4 acc[3][2][4] = {};

#pragma unroll 2
  for (int T = 0; T < 16; ++T) {
    __syncthreads();                          // drains stage(T); frees buf[T^1]
    if (T + 1 < 16) STAGE((T + 1) & 1, (T + 1) * 64);   // lands during compute(T)

    const unsigned short* At = sA[T & 1];
#pragma unroll
    for (int ks = 0; ks < 2; ++ks) {
      const int swk = (((ks * 4 + lg) ^ r7) << 3);
      bf16x8 afr[2];
#pragma unroll
      for (int mi = 0; mi < 2; ++mi)
        afr[mi] = *reinterpret_cast<const bf16x8*>(
            &At[(wm * 32 + mi * 16 + lr) * 64 + swk]);
#pragma unroll
      for (int mat = 0; mat < 3; ++mat) {
        const unsigned short* Bt = sB[T & 1][mat];
        bf16x8 bfr[4];
#pragma unroll
        for (int n = 0; n < 4; ++n)
          bfr[n] = *reinterpret_cast<const bf16x8*>(
              &Bt[(wn * 64 + n * 16 + lr) * 64 + swk]);
#pragma unroll
        for (int mi = 0; mi < 2; ++mi)
#pragma unroll
          for (int n = 0; n < 4; ++n)
            acc[mat][mi][n] = mfma16(afr[mi], bfr[n], acc[mat][mi][n]);
      }
    }
  }
#undef STAGE

  // epilogue: bias add, (K: reweight), cast, scatter into attention layouts
#pragma unroll
  for (int n = 0; n < 4; ++n) {
    const int col = n0 + wn * 64 + n * 16 + lr;   // feature 0..1023
    const int h = col >> 6, dk = col & 63;
    const float bqv = bq[col], bkv = bk[col], bvv = bv[col];
#pragma unroll
    for (int mi = 0; mi < 2; ++mi) {
#pragma unroll
      for (int r = 0; r < 4; ++r) {
        const int row = m0 + wm * 32 + mi * 16 + lg * 4 + r;  // token
        const int b = row >> 11, s = row & 2047;
        Qo[(((size_t)b * H_ + h) * S_ + s) * DK_ + dk] = bfbits(acc[0][mi][n][r] + bqv);
        Ko[(((size_t)b * H_ + h) * S_ + s) * DK_ + dk] =
            bfbits((acc[1][mi][n][r] + bkv) * (0.18033688011112042f * rw[row]));
        Vto[(((size_t)b * H_ + h) * DK_ + dk) * S_ + s] = bfbits(acc[2][mi][n][r] + bvv);
      }
    }
  }
}

// ---------------------------------------------------------------- flash attention
// (unchanged: 8 waves x 16 q-rows, paired q-blocks, KV=64 prefetch-dbuf,
// exp2-domain scores, no running max, XOR-swizzled LDS)
__global__ __launch_bounds__(512)
void SAA_attn(const unsigned short* __restrict__ Q,
              const unsigned short* __restrict__ Kb,
              const unsigned short* __restrict__ Vt,
              const int* __restrict__ maskp,
              unsigned short* __restrict__ Cb)
{
  const int pairid = blockIdx.x;                 // 0..7
  const int h = blockIdx.y, b = blockIdx.z;
  const int t = threadIdx.x, w = t >> 6, l = t & 63;
  const int lr = l & 15, lg = l >> 4;
  const int mask = maskp[0];

  __shared__ __attribute__((aligned(16))) unsigned short Kt[2][64 * 64];
  __shared__ __attribute__((aligned(16))) unsigned short Vl[2][64 * 64];
  __shared__ __attribute__((aligned(16))) unsigned short Pl[8][16 * 64];

  const size_t bh = (size_t)b * H_ + h;
  const unsigned short* Qbh = Q + bh * S_ * DK_;
  const unsigned short* Kbh = Kb + bh * S_ * DK_;
  const unsigned short* Vbh = Vt + bh * DK_ * S_;
  unsigned short* Pw = &Pl[w][0];

  const int r0 = t >> 3, cc0 = t & 7;
  const int sw0 = (cc0 ^ (r0 & 7)) * 8;

  for (int half = 0; half < 2; ++half) {
    const int qb = half ? (15 - pairid) : pairid;
    const int q0 = qb * 128;
    const int wq = q0 + w * 16;

    bf16x8 qf[2];
#pragma unroll
    for (int ks = 0; ks < 2; ks++)
      qf[ks] = *reinterpret_cast<const bf16x8*>(
          &Qbh[(size_t)(wq + lr) * DK_ + ks * 32 + lg * 8]);

    f32x4 acc[4] = {};
    float lrun[4] = {0.f, 0.f, 0.f, 0.f};

    const int nkt = mask ? (qb * 2 + 2) : (S_ / 64);
    const int wqmax = wq + 15;

    __syncthreads();

    gl_lds16(Kbh + (size_t)r0 * DK_ + sw0, &Kt[0][t * 8]);
    gl_lds16(Vbh + (size_t)r0 * S_ + sw0,  &Vl[0][t * 8]);
    int cur = 0;

    for (int kt = 0; kt < nkt; ++kt) {
      __syncthreads();
      if (kt + 1 < nkt) {
        const int kn = (kt + 1) * 64;
        const int nb = cur ^ 1;
        gl_lds16(Kbh + (size_t)(kn + r0) * DK_ + sw0, &Kt[nb][t * 8]);
        gl_lds16(Vbh + (size_t)r0 * S_ + kn + sw0,    &Vl[nb][t * 8]);
      }

      const int k0 = kt * 64;
      const bool active = (!mask) || (k0 <= wqmax);
      if (active) {
        const unsigned short* Kc = &Kt[cur][0];
        const unsigned short* Vc = &Vl[cur][0];

        f32x4 sc[4] = {};
#pragma unroll
        for (int ks = 0; ks < 2; ++ks) {
          const int swk = (((ks * 4 + lg) ^ (lr & 7)) << 3);
#pragma unroll
          for (int t2 = 0; t2 < 4; ++t2) {
            bf16x8 kf = *reinterpret_cast<const bf16x8*>(&Kc[(t2 * 16 + lr) * 64 + swk]);
            sc[t2] = mfma16(qf[ks], kf, sc[t2]);
          }
        }

        const bool needmask = mask && (k0 + 63 > wq);

#pragma unroll
        for (int r = 0; r < 4; r++) {
          const int row = wq + lg * 4 + r;
          float v0 = sc[0][r], v1 = sc[1][r];
          float v2 = sc[2][r], v3 = sc[3][r];
          if (needmask) {
            if (k0 + lr      > row) v0 = -1e30f;
            if (k0 + 16 + lr > row) v1 = -1e30f;
            if (k0 + 32 + lr > row) v2 = -1e30f;
            if (k0 + 48 + lr > row) v3 = -1e30f;
          }
          const float p0 = __builtin_amdgcn_exp2f(v0);
          const float p1 = __builtin_amdgcn_exp2f(v1);
          const float p2 = __builtin_amdgcn_exp2f(v2);
          const float p3 = __builtin_amdgcn_exp2f(v3);
          lrun[r] += (p0 + p1) + (p2 + p3);
          const int prow = lg * 4 + r;
          const int pr7 = prow & 7;
          const int pbase = prow * 64 + (lr & 7);
          const int hi = lr >> 3;
          Pw[pbase + (((0 + hi) ^ pr7) << 3)] = bfbits(p0);
          Pw[pbase + (((2 + hi) ^ pr7) << 3)] = bfbits(p1);
          Pw[pbase + (((4 + hi) ^ pr7) << 3)] = bfbits(p2);
          Pw[pbase + (((6 + hi) ^ pr7) << 3)] = bfbits(p3);
        }

#pragma unroll
        for (int ks = 0; ks < 2; ++ks) {
          const int swk = (((ks * 4 + lg) ^ (lr & 7)) << 3);
          bf16x8 pf = *reinterpret_cast<const bf16x8*>(&Pw[lr * 64 + swk]);
#pragma unroll
          for (int dt = 0; dt < 4; ++dt) {
            bf16x8 vf = *reinterpret_cast<const bf16x8*>(&Vc[(dt * 16 + lr) * 64 + swk]);
            acc[dt] = mfma16(pf, vf, acc[dt]);
          }
        }
      }
      cur ^= 1;
    }

#pragma unroll
    for (int r = 0; r < 4; r++) {
      float rs = lrun[r];
      rs += __shfl_xor(rs, 1);
      rs += __shfl_xor(rs, 2);
      rs += __shfl_xor(rs, 4);
      rs += __shfl_xor(rs, 8);
      lrun[r] = __builtin_amdgcn_rcpf(rs);
    }
#pragma unroll
    for (int dt = 0; dt < 4; dt++) {
#pragma unroll
      for (int r = 0; r < 4; r++) {
        const int row = wq + lg * 4 + r;
        const int col = h * DK_ + dt * 16 + lr;
        Cb[((size_t)b * S_ + row) * D_ + col] = bfbits(acc[dt][r] * lrun[r]);
      }
    }
  }
}

// ---------------------------------------------------------------- output GEMM
// 128x128 tile, BK=64 XOR-swizzled, PREFETCH double-buffer (same overlap fix),
// 256 threads, LDS 64KB -> 2 blocks/CU.
__global__ __launch_bounds__(256)
void SAA_gemm_out(const unsigned short* __restrict__ Cb,
                  const unsigned short* __restrict__ Wob,
                  const float* __restrict__ bo,
                  float* __restrict__ Y)
{
  const int K = D_;
  __shared__ __attribute__((aligned(16))) unsigned short lA[2][128 * 64];
  __shared__ __attribute__((aligned(16))) unsigned short lB[2][128 * 64];

  const int t = threadIdx.x;
  const int w = t >> 6, l = t & 63;
  const int wr = w >> 1, wc = w & 1;
  const int lr = l & 15, lg = l >> 4;
  const int r7 = lr & 7;

  const int m0 = blockIdx.y * 128;
  const int n0 = blockIdx.x * 128;

  const unsigned short* gA = Cb + (size_t)m0 * K;
  const unsigned short* gB = Wob + (size_t)n0 * K;

  int srow[4], soff[4];
#pragma unroll
  for (int i = 0; i < 4; i++) {
    const int c = i * 256 + t;
    srow[i] = c >> 3;
    soff[i] = ((c & 7) ^ (srow[i] & 7)) * 8;
  }

#define STAGEO(s, k0)                                                         \
  do {                                                                        \
    _Pragma("unroll")                                                         \
    for (int i = 0; i < 4; i++) {                                             \
      const size_t go = (size_t)srow[i] * K + (k0) + soff[i];                 \
      const int dl = (i * 256 + t) * 8;                                       \
      gl_lds16(gA + go, &lA[s][dl]);                                          \
      gl_lds16(gB + go, &lB[s][dl]);                                          \
    }                                                                         \
  } while (0)

  STAGEO(0, 0);

  f32x4 acc[4][4] = {};

#pragma unroll 2
  for (int T = 0; T < 16; ++T) {
    __syncthreads();
    if (T + 1 < 16) STAGEO((T + 1) & 1, (T + 1) * 64);

    const unsigned short* At = lA[T & 1];
    const unsigned short* Bt = lB[T & 1];
#pragma unroll
    for (int ks = 0; ks < 2; ks++) {
      const int swk = (((ks * 4 + lg) ^ r7) << 3);
      bf16x8 af[4], bfr[4];
#pragma unroll
      for (int i = 0; i < 4; i++)
        af[i] = *reinterpret_cast<const bf16x8*>(&At[(wr * 64 + i * 16 + lr) * 64 + swk]);
#pragma unroll
      for (int j = 0; j < 4; j++)
        bfr[j] = *reinterpret_cast<const bf16x8*>(&Bt[(wc * 64 + j * 16 + lr) * 64 + swk]);
#pragma unroll
      for (int i = 0; i < 4; i++)
#pragma unroll
        for (int j = 0; j < 4; j++)
          acc[i][j] = mfma16(af[i], bfr[j], acc[i][j]);
    }
  }
#undef STAGEO

#pragma unroll
  for (int j = 0; j < 4; j++) {
    const int col = n0 + wc * 64 + j * 16 + lr;
    const float bsv = bo[col];
#pragma unroll
    for (int i = 0; i < 4; i++) {
#pragma unroll
      for (int r = 0; r < 4; r++) {
        const int row = m0 + wr * 64 + i * 16 + lg * 4 + r;
        Y[(size_t)row * D_ + col] = acc[i][j][r] + bsv;
      }
    }
  }
}

// ---------------------------------------------------------------- launch
extern "C" void kernel_launch(void* const* d_in, const int* in_sizes, int n_in,
                              void* d_out, int out_size, void* d_ws, size_t ws_size,
                              hipStream_t stream) {
  const float* input = (const float*)d_in[0];
  const float* rw    = (const float*)d_in[1];
  const int*   maskp = (const int*)d_in[2];
  const float* Wq = (const float*)d_in[3];
  const float* bq = (const float*)d_in[4];
  const float* Wk = (const float*)d_in[5];
  const float* bk = (const float*)d_in[6];
  const float* Wv = (const float*)d_in[7];
  const float* bv = (const float*)d_in[8];
  const float* Wo = (const float*)d_in[9];
  const float* bo = (const float*)d_in[10];

  char* ws = (char*)d_ws;
  unsigned short* Xb  = (unsigned short*)(ws);                 // 16 MB (reused as Cb)
  unsigned short* Wqb = (unsigned short*)(ws + (16u << 20));   // 2 MB each
  unsigned short* Wkb = (unsigned short*)(ws + (18u << 20));
  unsigned short* Wvb = (unsigned short*)(ws + (20u << 20));
  unsigned short* Wob = (unsigned short*)(ws + (22u << 20));
  unsigned short* Qo  = (unsigned short*)(ws + (24u << 20));   // 16 MB
  unsigned short* Ko  = (unsigned short*)(ws + (40u << 20));   // 16 MB
  unsigned short* Vto = (unsigned short*)(ws + (56u << 20));   // 16 MB
  unsigned short* Cb  = Xb;   // Xb dead after QKV GEMM

  SAA_cast_bf16<<<2048, 256, 0, stream>>>(input, Xb, (B_ * S_ * D_) / 4);
  SAA_cast4<<<dim3(512, 4), 256, 0, stream>>>(Wq, Wk, Wv, Wo, Wqb, Wkb, Wvb, Wob,
                                              (D_ * D_) / 4);

  SAA_gemm_qkv<<<dim3(8, 64), 512, 0, stream>>>(Xb, Wqb, Wkb, Wvb, bq, bk, bv, rw,
                                                Qo, Ko, Vto);
  SAA_attn<<<dim3(8, 16, 4), 512, 0, stream>>>(Qo, Ko, Vto, maskp, Cb);
  SAA_gemm_out<<<dim3(8, 64), 256, 0, stream>>>(Cb, Wob, bo, (float*)d_out);
}